// Round 2
// 592.995 us; speedup vs baseline: 1.0927x; 1.0927x over previous
//
#include <hip/hip_runtime.h>
#include <math.h>
#include <stdint.h>

typedef _Float16 f16x8 __attribute__((ext_vector_type(8)));
typedef float    f32x4 __attribute__((ext_vector_type(4)));

#define NB    8192
#define V_    25
#define KS_   0.25505003938643f      // 32^-0.5 * log2(e)

// ---------------------------------------------------------------------------
// Pre-kernel: split W (512x256 fp32) into per-lane MFMA B-fragments in d_ws.
// Tile index idx = C*16 + T2, C = half*8 + ch (k-chunk), T2 = n-tile in half.
// Block of 2048 B per idx: [0,1024) = Bh frags (64 lanes x 16B, lane-linear),
//                          [1024,2048) = Bl frags.
// Lane l -> l15=l&15, q4=l>>4; frag element jj: W[half*256 + T2*16 + l15]
//                                               [ch*32 + q4*8 + jj]
// Main kernel reads lane-linear 16B -> perfectly coalesced dwordx4, L2-hot.
// ---------------------------------------------------------------------------
__global__ __launch_bounds__(256)
void prep_w(const float* __restrict__ W, _Float16* __restrict__ ws) {
    int tid  = blockIdx.x * 256 + threadIdx.x;   // 16384 threads
    int lane = tid & 63;
    int idx  = tid >> 6;                         // 0..255
    int C    = idx >> 4;
    int T2   = idx & 15;
    int half = C >> 3, ch = C & 7;
    int l15  = lane & 15, q4 = lane >> 4;
    const float* src = W + (size_t)(half*256 + T2*16 + l15) * 256 + ch*32 + q4*8;
    f16x8 hi, lo;
    #pragma unroll
    for (int j = 0; j < 8; ++j) {
        float w = src[j];
        _Float16 hh = (_Float16)w;
        hi[j] = hh;
        lo[j] = (_Float16)(w - (float)hh);
    }
    char* base = (char*)ws + (size_t)idx * 2048 + lane * 16;
    *(f16x8*)base          = hi;
    *(f16x8*)(base + 1024) = lo;
}

// ---------------------------------------------------------------------------
struct __align__(16) SMem {
    union {
        float xbuf[256][36];                    // 36864 B : phase0 + LN stats
        struct {
            _Float16 ysh[32][264];              // 16896 B : A hi [v][c]
            _Float16 ysl[32][264];              // 16896 B : A lo
        } g;                                    // 33792 B
        _Float16 qk[4][2][32][72];              // 36864 B : per-wave QK staging
        // qk[wave][hi/lo][row v][col]: col 0..31 = Q chans of head, 32..63 = K,
        // 64..71 pad (row pitch 144 B = 36 dw; 36%32=4 -> 2-way on frag reads,
        // which is free).
    } u;
    float s_mu[32];
    float s_rs[32];
};

__global__ __launch_bounds__(256, 3)
void fused_ln_qk_attn(const float* __restrict__ x,
                      const float* __restrict__ gamma,
                      const float* __restrict__ beta,
                      const _Float16* __restrict__ wsp,
                      const float* __restrict__ bias,
                      float* __restrict__ out)
{
    __shared__ SMem sm;

    const int tid  = threadIdx.x;
    const int lane = tid & 63;
    const int wv   = tid >> 6;
    const int l15  = lane & 15;
    const int q4   = lane >> 4;
    const int nt   = blockIdx.x;
    const int n    = nt >> 7;
    const int t    = nt & 127;
    const int base = n * 819200 + t * 25;       // x[n][c][t][v]

    // ---------------- Phase 0: load x slice (thread owns channel c=tid) ------
    float xv[32];
    {
        const float* xr = x + base + tid * 3200;
        #pragma unroll
        for (int v = 0; v < V_; ++v) xv[v] = xr[v];
        #pragma unroll
        for (int v = V_; v < 32; ++v) xv[v] = 0.0f;
        #pragma unroll
        for (int i = 0; i < 8; ++i) {
            float4 f;
            f.x = xv[i*4+0]; f.y = xv[i*4+1]; f.z = xv[i*4+2]; f.w = xv[i*4+3];
            *(float4*)&sm.u.xbuf[tid][i*4] = f;
        }
    }
    __syncthreads();

    // ---------------- LN stats ------------------------------------------------
    {
        const int v = tid >> 3;
        const int j = tid & 7;
        float s1 = 0.0f, s2 = 0.0f;
        #pragma unroll 4
        for (int m = 0; m < 32; ++m) {
            float val = sm.u.xbuf[j + 8*m][v];
            s1 += val; s2 += val * val;
        }
        s1 += __shfl_xor(s1, 1); s2 += __shfl_xor(s2, 1);
        s1 += __shfl_xor(s1, 2); s2 += __shfl_xor(s2, 2);
        s1 += __shfl_xor(s1, 4); s2 += __shfl_xor(s2, 4);
        if (j == 0) {
            if (v < V_) {
                float mu  = s1 * (1.0f/256.0f);
                float var = s2 * (1.0f/256.0f) - mu * mu;
                sm.s_mu[v] = mu;
                sm.s_rs[v] = rsqrtf(var + 1e-5f);
            } else { sm.s_mu[v] = 0.0f; sm.s_rs[v] = 0.0f; }
        }
    }
    __syncthreads();   // xbuf reads done -> ysh/ysl (aliases) may be written

    // ---------------- Normalize + f16 hi/lo split -> ysh/ysl[v][c] ------------
    {
        const float g  = gamma[tid];
        const float be = beta[tid];
        #pragma unroll
        for (int v = 0; v < V_; ++v) {
            float val = (xv[v] - sm.s_mu[v]) * sm.s_rs[v] * g + be;
            _Float16 h = (_Float16)val;
            sm.u.g.ysh[v][tid] = h;
            sm.u.g.ysl[v][tid] = (_Float16)(val - (float)h);
        }
        // rows 25..31 stale: dots from them are masked in softmax
    }
    __syncthreads();   // ysh/ysl visible to all waves; K-loop is barrier-free

    // bias for this lane's 16 output columns
    float bv[2][4];
    #pragma unroll
    for (int h = 0; h < 2; ++h)
        #pragma unroll
        for (int j = 0; j < 4; ++j)
            bv[h][j] = bias[h*256 + (wv*4 + j)*16 + l15];

    // ---------------- GEMM: P[v][e] = sum_c ys[v][c]*W[e][c], f16 split-x3 ----
    // B fragments stream L2 -> VGPR directly (coalesced dwordx4, no LDS, no
    // barriers). A fragments from LDS, reused across both halves per k-chunk.
    f32x4 acc[2][2][4];
    #pragma unroll
    for (int h = 0; h < 2; ++h)
        #pragma unroll
        for (int m = 0; m < 2; ++m)
            #pragma unroll
            for (int j = 0; j < 4; ++j)
                acc[h][m][j] = (f32x4){0.f, 0.f, 0.f, 0.f};

    const char* bbase = (const char*)wsp + (size_t)lane * 16 + (size_t)(wv*4) * 2048;

    for (int ch = 0; ch < 8; ++ch) {
        const int kb = ch*32 + q4*8;
        f16x8 Ah0 = *(const f16x8*)&sm.u.g.ysh[l15][kb];
        f16x8 Ah1 = *(const f16x8*)&sm.u.g.ysh[16 + l15][kb];
        f16x8 Al0 = *(const f16x8*)&sm.u.g.ysl[l15][kb];
        f16x8 Al1 = *(const f16x8*)&sm.u.g.ysl[16 + l15][kb];
        #pragma unroll
        for (int half = 0; half < 2; ++half) {
            const char* cb = bbase + (size_t)(half*8 + ch) * 16 * 2048;
            #pragma unroll
            for (int j = 0; j < 4; ++j) {
                const char* pj = cb + (size_t)j * 2048;
                f16x8 Bh = *(const f16x8*)pj;
                f16x8 Bl = *(const f16x8*)(pj + 1024);
                acc[half][0][j] = __builtin_amdgcn_mfma_f32_16x16x32_f16(Ah0, Bh, acc[half][0][j], 0, 0, 0);
                acc[half][0][j] = __builtin_amdgcn_mfma_f32_16x16x32_f16(Al0, Bh, acc[half][0][j], 0, 0, 0);
                acc[half][0][j] = __builtin_amdgcn_mfma_f32_16x16x32_f16(Ah0, Bl, acc[half][0][j], 0, 0, 0);
                acc[half][1][j] = __builtin_amdgcn_mfma_f32_16x16x32_f16(Ah1, Bh, acc[half][1][j], 0, 0, 0);
                acc[half][1][j] = __builtin_amdgcn_mfma_f32_16x16x32_f16(Al1, Bh, acc[half][1][j], 0, 0, 0);
                acc[half][1][j] = __builtin_amdgcn_mfma_f32_16x16x32_f16(Ah1, Bl, acc[half][1][j], 0, 0, 0);
            }
        }
    }
    __syncthreads();   // all waves' ysh/ysl reads done; qk staging aliases it

    // ---------------- Attention via MFMA --------------------------------------
    // Wave wv's GEMM columns are exactly the Q and K channels of heads
    // 2wv, 2wv+1 (e_q = wv*64 + j*16 + l15, head = j>>1). Per head: stage
    // Q,K (+bias) as f16 hi/lo into the wave-private qk tile, read back
    // A=K / B=Q fragments (row = l15 (+16), k = q4*8..+8 -> same pattern as
    // the projection A-frags), compute D[j][i] = K·Q^T with 3-term split.
    // C-layout: i(col)=l15, j(row)=q4*4+reg  [verified m89/m91]
    // -> softmax over keys j = 7 in-lane ops + shfl_xor(16) + shfl_xor(32).
    // Rows v>=25 / keys j>=25 hold garbage; masked to -inf before max, so
    // they contribute exp2(-huge)=0.  acc[j=2,3] stays live through head 0.
    #pragma unroll
    for (int hh = 0; hh < 2; ++hh) {
        _Float16 (*qh)[72] = sm.u.qk[wv][0];
        _Float16 (*ql)[72] = sm.u.qk[wv][1];

        // ---- stage this head's Q,K (hi/lo f16) into per-wave LDS ----
        #pragma unroll
        for (int half = 0; half < 2; ++half)
            #pragma unroll
            for (int jj = 0; jj < 2; ++jj) {
                const int  j   = 2*hh + jj;
                const float bb = bv[half][j];
                const int  col = half*32 + jj*16 + l15;
                #pragma unroll
                for (int mt = 0; mt < 2; ++mt)
                    #pragma unroll
                    for (int r = 0; r < 4; ++r) {
                        const int row = mt*16 + q4*4 + r;
                        float val  = acc[half][mt][j][r] + bb;
                        _Float16 h = (_Float16)val;
                        qh[row][col] = h;
                        ql[row][col] = (_Float16)(val - (float)h);
                    }
            }
        // same-wave DS ops execute in order; compiler inserts lgkmcnt waits

        // ---- fragment reads (A = K rows, B = Q rows) ----
        f16x8 Kh[2], Kl[2], Qh[2], Ql[2];
        #pragma unroll
        for (int tt = 0; tt < 2; ++tt) {
            const int rr = tt*16 + l15;
            Kh[tt] = *(const f16x8*)&qh[rr][32 + q4*8];
            Kl[tt] = *(const f16x8*)&ql[rr][32 + q4*8];
            Qh[tt] = *(const f16x8*)&qh[rr][q4*8];
            Ql[tt] = *(const f16x8*)&ql[rr][q4*8];
        }

        // ---- D[jt][it] = K·Q^T, split-x3 (12 MFMA per head) ----
        f32x4 D[2][2];
        #pragma unroll
        for (int jt = 0; jt < 2; ++jt)
            #pragma unroll
            for (int it = 0; it < 2; ++it) {
                f32x4 d = (f32x4){0.f, 0.f, 0.f, 0.f};
                d = __builtin_amdgcn_mfma_f32_16x16x32_f16(Kh[jt], Qh[it], d, 0, 0, 0);
                d = __builtin_amdgcn_mfma_f32_16x16x32_f16(Kl[jt], Qh[it], d, 0, 0, 0);
                d = __builtin_amdgcn_mfma_f32_16x16x32_f16(Kh[jt], Ql[it], d, 0, 0, 0);
                D[jt][it] = d;
            }

        // ---- softmax over keys + store ----
        float* op = out + (size_t)nt * 5000 + (wv*2 + hh) * 625;
        #pragma unroll
        for (int it = 0; it < 2; ++it) {
            const int i = it*16 + l15;          // query index (col = l15)
            float pv[2][4];
            float mx = -3.0e38f;
            #pragma unroll
            for (int jt = 0; jt < 2; ++jt)
                #pragma unroll
                for (int r = 0; r < 4; ++r) {
                    const int j = jt*16 + q4*4 + r;   // key index (row)
                    float v = (j < V_) ? D[jt][it][r] : -3.0e38f;
                    pv[jt][r] = v;
                    mx = fmaxf(mx, v);
                }
            mx = fmaxf(mx, __shfl_xor(mx, 16));
            mx = fmaxf(mx, __shfl_xor(mx, 32));
            float sum = 0.0f;
            #pragma unroll
            for (int jt = 0; jt < 2; ++jt)
                #pragma unroll
                for (int r = 0; r < 4; ++r) {
                    float e = exp2f((pv[jt][r] - mx) * KS_);
                    pv[jt][r] = e;
                    sum += e;
                }
            sum += __shfl_xor(sum, 16);
            sum += __shfl_xor(sum, 32);
            const float rcp = 1.0f / sum;
            if (i < V_) {
                #pragma unroll
                for (int jt = 0; jt < 2; ++jt)
                    #pragma unroll
                    for (int r = 0; r < 4; ++r) {
                        const int j = jt*16 + q4*4 + r;
                        if (j < V_) op[i*25 + j] = pv[jt][r] * rcp;
                    }
            }
        }
    }
}

extern "C" void kernel_launch(void* const* d_in, const int* in_sizes, int n_in,
                              void* d_out, int out_size, void* d_ws, size_t ws_size,
                              hipStream_t stream) {
    const float* x     = (const float*)d_in[0];
    const float* gamma = (const float*)d_in[1];
    const float* beta  = (const float*)d_in[2];
    const float* W     = (const float*)d_in[3];
    const float* b     = (const float*)d_in[4];
    _Float16* wsp = (_Float16*)d_ws;            // 512 KB fragment cache
    float* out = (float*)d_out;

    prep_w<<<dim3(64), dim3(256), 0, stream>>>(W, wsp);
    fused_ln_qk_attn<<<dim3(NB), dim3(256), 0, stream>>>(x, gamma, beta, wsp, b, out);
}

// Round 3
// 542.124 us; speedup vs baseline: 1.1953x; 1.0938x over previous
//
#include <hip/hip_runtime.h>
#include <math.h>
#include <stdint.h>

typedef _Float16 f16x8 __attribute__((ext_vector_type(8)));
typedef float    f32x4 __attribute__((ext_vector_type(4)));

#define NB    8192
#define V_    25
#define KS_   0.25505003938643f      // 32^-0.5 * log2(e)

// ---------------------------------------------------------------------------
// Pre-kernel: split W (512x256 fp32) into per-lane MFMA B-fragments in d_ws.
// (unchanged from previous round — see comments there)
// ---------------------------------------------------------------------------
__global__ __launch_bounds__(256)
void prep_w(const float* __restrict__ W, _Float16* __restrict__ ws) {
    int tid  = blockIdx.x * 256 + threadIdx.x;   // 16384 threads
    int lane = tid & 63;
    int idx  = tid >> 6;                         // 0..255
    int C    = idx >> 4;
    int T2   = idx & 15;
    int half = C >> 3, ch = C & 7;
    int l15  = lane & 15, q4 = lane >> 4;
    const float* src = W + (size_t)(half*256 + T2*16 + l15) * 256 + ch*32 + q4*8;
    f16x8 hi, lo;
    #pragma unroll
    for (int j = 0; j < 8; ++j) {
        float w = src[j];
        _Float16 hh = (_Float16)w;
        hi[j] = hh;
        lo[j] = (_Float16)(w - (float)hh);
    }
    char* base = (char*)ws + (size_t)idx * 2048 + lane * 16;
    *(f16x8*)base          = hi;
    *(f16x8*)(base + 1024) = lo;
}

// ---------------------------------------------------------------------------
// LDS diet: no xbuf (stats read f16 hi/lo rows directly), qk padless with
// XOR swizzle. Total 34048 B -> 4 blocks/CU.
// ---------------------------------------------------------------------------
struct __align__(16) SMem {
    union {
        struct {
            _Float16 ysh[32][264];              // 16896 B : A hi [v][c]
            _Float16 ysl[32][264];              // 16896 B : A lo
        } g;                                    // 33792 B
        _Float16 qk[4][2][32][64];              // 32768 B : per-wave QK staging
        // qk[wave][hi/lo][row v][col 0..31=Q, 32..63=K], byte offset within
        // the [32][64] tile XOR-swizzled with ((row&7)<<4): b128 frag reads
        // (64 lanes, rows 0..15/16..31, 16B cols) land on 64 distinct 16B
        // slots -> conflict-free; staging b16 writes stay 32B-contiguous
        // per 16-lane group (same row -> same XOR) -> free.
    } u;
    float s_mu[32];
    float s_rs[32];
};

__global__ __launch_bounds__(256, 4)
void fused_ln_qk_attn(const float* __restrict__ x,
                      const float* __restrict__ gamma,
                      const float* __restrict__ beta,
                      const _Float16* __restrict__ wsp,
                      const float* __restrict__ bias,
                      float* __restrict__ out)
{
    __shared__ SMem sm;

    const int tid  = threadIdx.x;
    const int lane = tid & 63;
    const int wv   = tid >> 6;
    const int l15  = lane & 15;
    const int q4   = lane >> 4;
    const int nt   = blockIdx.x;
    const int n    = nt >> 7;
    const int t    = nt & 127;
    const int base = n * 819200 + t * 25;       // x[n][c][t][v]

    // ---------------- Phase 0: load x slice (thread owns channel c=tid) ------
    // Raw values kept in registers; f16 hi/lo staged to LDS only for the
    // stats transpose (hi+lo sum is exact to ~2^-22 relative).
    float xv[V_];
    {
        const float* xr = x + base + tid * 3200;
        #pragma unroll
        for (int v = 0; v < V_; ++v) xv[v] = xr[v];
        #pragma unroll
        for (int v = 0; v < V_; ++v) {
            _Float16 h = (_Float16)xv[v];
            sm.u.g.ysh[v][tid] = h;
            sm.u.g.ysl[v][tid] = (_Float16)(xv[v] - (float)h);
        }
        // rows 25..31 uninitialized: stats for them are discarded below
    }
    __syncthreads();

    // ---------------- LN stats (thread = (v, j): sums cols [32j, 32j+32)) ----
    {
        const int v = tid >> 3;
        const int j = tid & 7;
        float s1 = 0.0f, s2 = 0.0f;
        #pragma unroll
        for (int m2 = 0; m2 < 4; ++m2) {
            f16x8 hv = *(const f16x8*)&sm.u.g.ysh[v][j*32 + m2*8];
            f16x8 lv = *(const f16x8*)&sm.u.g.ysl[v][j*32 + m2*8];
            #pragma unroll
            for (int e = 0; e < 8; ++e) {
                float val = (float)hv[e] + (float)lv[e];
                s1 += val; s2 += val * val;
            }
        }
        s1 += __shfl_xor(s1, 1); s2 += __shfl_xor(s2, 1);
        s1 += __shfl_xor(s1, 2); s2 += __shfl_xor(s2, 2);
        s1 += __shfl_xor(s1, 4); s2 += __shfl_xor(s2, 4);
        if (j == 0) {
            if (v < V_) {
                float mu  = s1 * (1.0f/256.0f);
                float var = s2 * (1.0f/256.0f) - mu * mu;
                sm.s_mu[v] = mu;
                sm.s_rs[v] = rsqrtf(var + 1e-5f);
            } else { sm.s_mu[v] = 0.0f; sm.s_rs[v] = 0.0f; }
        }
    }
    __syncthreads();   // raw ysh/ysl reads done -> may be overwritten

    // ---------------- Normalize (from regs) + f16 hi/lo split -> ysh/ysl -----
    {
        const float g  = gamma[tid];
        const float be = beta[tid];
        #pragma unroll
        for (int v = 0; v < V_; ++v) {
            float val = (xv[v] - sm.s_mu[v]) * sm.s_rs[v] * g + be;
            _Float16 h = (_Float16)val;
            sm.u.g.ysh[v][tid] = h;
            sm.u.g.ysl[v][tid] = (_Float16)(val - (float)h);
        }
        // rows 25..31 stale: dots from them are masked in softmax
    }
    __syncthreads();   // ysh/ysl visible to all waves; K-loop is barrier-free

    // bias for this lane's 16 output columns
    float bv[2][4];
    #pragma unroll
    for (int h = 0; h < 2; ++h)
        #pragma unroll
        for (int j = 0; j < 4; ++j)
            bv[h][j] = bias[h*256 + (wv*4 + j)*16 + l15];

    // ---------------- GEMM: P[v][e] = sum_c ys[v][c]*W[e][c], f16 split-x3 ----
    f32x4 acc[2][2][4];
    #pragma unroll
    for (int h = 0; h < 2; ++h)
        #pragma unroll
        for (int m = 0; m < 2; ++m)
            #pragma unroll
            for (int j = 0; j < 4; ++j)
                acc[h][m][j] = (f32x4){0.f, 0.f, 0.f, 0.f};

    const char* bbase = (const char*)wsp + (size_t)lane * 16 + (size_t)(wv*4) * 2048;

    for (int ch = 0; ch < 8; ++ch) {
        const int kb = ch*32 + q4*8;
        f16x8 Ah0 = *(const f16x8*)&sm.u.g.ysh[l15][kb];
        f16x8 Ah1 = *(const f16x8*)&sm.u.g.ysh[16 + l15][kb];
        f16x8 Al0 = *(const f16x8*)&sm.u.g.ysl[l15][kb];
        f16x8 Al1 = *(const f16x8*)&sm.u.g.ysl[16 + l15][kb];
        #pragma unroll
        for (int half = 0; half < 2; ++half) {
            const char* cb = bbase + (size_t)(half*8 + ch) * 16 * 2048;
            #pragma unroll
            for (int j = 0; j < 4; ++j) {
                const char* pj = cb + (size_t)j * 2048;
                f16x8 Bh = *(const f16x8*)pj;
                f16x8 Bl = *(const f16x8*)(pj + 1024);
                acc[half][0][j] = __builtin_amdgcn_mfma_f32_16x16x32_f16(Ah0, Bh, acc[half][0][j], 0, 0, 0);
                acc[half][0][j] = __builtin_amdgcn_mfma_f32_16x16x32_f16(Al0, Bh, acc[half][0][j], 0, 0, 0);
                acc[half][0][j] = __builtin_amdgcn_mfma_f32_16x16x32_f16(Ah0, Bl, acc[half][0][j], 0, 0, 0);
                acc[half][1][j] = __builtin_amdgcn_mfma_f32_16x16x32_f16(Ah1, Bh, acc[half][1][j], 0, 0, 0);
                acc[half][1][j] = __builtin_amdgcn_mfma_f32_16x16x32_f16(Al1, Bh, acc[half][1][j], 0, 0, 0);
                acc[half][1][j] = __builtin_amdgcn_mfma_f32_16x16x32_f16(Ah1, Bl, acc[half][1][j], 0, 0, 0);
            }
        }
    }
    __syncthreads();   // all waves' ysh/ysl reads done; qk staging aliases it

    // ---------------- Attention via MFMA (per-wave, 2 heads) ------------------
    // See previous round's comments; qk tile now XOR-swizzled ((row&7)<<4).
    char* qh = (char*)&sm.u.qk[wv][0][0][0];
    char* ql = (char*)&sm.u.qk[wv][1][0][0];

    #pragma unroll
    for (int hh = 0; hh < 2; ++hh) {
        // ---- stage this head's Q,K (hi/lo f16) into per-wave LDS ----
        #pragma unroll
        for (int half = 0; half < 2; ++half)
            #pragma unroll
            for (int jj = 0; jj < 2; ++jj) {
                const int  j   = 2*hh + jj;
                const float bb = bv[half][j];
                const int  col = half*32 + jj*16 + l15;
                #pragma unroll
                for (int mt = 0; mt < 2; ++mt)
                    #pragma unroll
                    for (int r = 0; r < 4; ++r) {
                        const int row = mt*16 + q4*4 + r;
                        const int off = (row*128 + col*2) ^ ((row & 7) << 4);
                        float val  = acc[half][mt][j][r] + bb;
                        _Float16 h = (_Float16)val;
                        *(_Float16*)(qh + off) = h;
                        *(_Float16*)(ql + off) = (_Float16)(val - (float)h);
                    }
            }
        // same-wave DS ops execute in order; compiler inserts lgkmcnt waits

        // ---- fragment reads (A = K rows, B = Q rows) ----
        f16x8 Kh[2], Kl[2], Qh[2], Ql[2];
        #pragma unroll
        for (int tt = 0; tt < 2; ++tt) {
            const int rr  = tt*16 + l15;
            const int swz = (rr & 7) << 4;
            const int oK  = (rr*128 + 64 + q4*16) ^ swz;
            const int oQ  = (rr*128 +      q4*16) ^ swz;
            Kh[tt] = *(const f16x8*)(qh + oK);
            Kl[tt] = *(const f16x8*)(ql + oK);
            Qh[tt] = *(const f16x8*)(qh + oQ);
            Ql[tt] = *(const f16x8*)(ql + oQ);
        }

        // ---- D[jt][it] = K·Q^T, split-x3 (12 MFMA per head) ----
        f32x4 D[2][2];
        #pragma unroll
        for (int jt = 0; jt < 2; ++jt)
            #pragma unroll
            for (int it = 0; it < 2; ++it) {
                f32x4 d = (f32x4){0.f, 0.f, 0.f, 0.f};
                d = __builtin_amdgcn_mfma_f32_16x16x32_f16(Kh[jt], Qh[it], d, 0, 0, 0);
                d = __builtin_amdgcn_mfma_f32_16x16x32_f16(Kl[jt], Qh[it], d, 0, 0, 0);
                d = __builtin_amdgcn_mfma_f32_16x16x32_f16(Kh[jt], Ql[it], d, 0, 0, 0);
                D[jt][it] = d;
            }

        // ---- softmax over keys + store ----
        float* op = out + (size_t)nt * 5000 + (wv*2 + hh) * 625;
        #pragma unroll
        for (int it = 0; it < 2; ++it) {
            const int i = it*16 + l15;          // query index (col = l15)
            float pv[2][4];
            float mx = -3.0e38f;
            #pragma unroll
            for (int jt = 0; jt < 2; ++jt)
                #pragma unroll
                for (int r = 0; r < 4; ++r) {
                    const int j = jt*16 + q4*4 + r;   // key index (row)
                    float v = (j < V_) ? D[jt][it][r] : -3.0e38f;
                    pv[jt][r] = v;
                    mx = fmaxf(mx, v);
                }
            mx = fmaxf(mx, __shfl_xor(mx, 16));
            mx = fmaxf(mx, __shfl_xor(mx, 32));
            float sum = 0.0f;
            #pragma unroll
            for (int jt = 0; jt < 2; ++jt)
                #pragma unroll
                for (int r = 0; r < 4; ++r) {
                    float e = exp2f((pv[jt][r] - mx) * KS_);
                    pv[jt][r] = e;
                    sum += e;
                }
            sum += __shfl_xor(sum, 16);
            sum += __shfl_xor(sum, 32);
            const float rcp = 1.0f / sum;
            if (i < V_) {
                #pragma unroll
                for (int jt = 0; jt < 2; ++jt)
                    #pragma unroll
                    for (int r = 0; r < 4; ++r) {
                        const int j = jt*16 + q4*4 + r;
                        if (j < V_) op[i*25 + j] = pv[jt][r] * rcp;
                    }
            }
        }
    }
}

extern "C" void kernel_launch(void* const* d_in, const int* in_sizes, int n_in,
                              void* d_out, int out_size, void* d_ws, size_t ws_size,
                              hipStream_t stream) {
    const float* x     = (const float*)d_in[0];
    const float* gamma = (const float*)d_in[1];
    const float* beta  = (const float*)d_in[2];
    const float* W     = (const float*)d_in[3];
    const float* b     = (const float*)d_in[4];
    _Float16* wsp = (_Float16*)d_ws;            // 512 KB fragment cache
    float* out = (float*)d_out;

    prep_w<<<dim3(64), dim3(256), 0, stream>>>(W, wsp);
    fused_ln_qk_attn<<<dim3(NB), dim3(256), 0, stream>>>(x, gamma, beta, wsp, b, out);
}